// Round 7
// baseline (11193.379 us; speedup 1.0000x reference)
//
#include <hip/hip_runtime.h>
#include <hip/hip_bf16.h>
#include <cfloat>

// FPS reference-matching, round 7. Eliminated so far (distinct deterministic
// absmax each): round-per-op fp32 (R1/R2/R6 bit-identical, asm-forced),
// textbook fma chain fma(dz,dz,fma(dy,dy,dx*dx)) (R3), all-fp64 (R4),
// fp64->fp32-store (R5). Divergence onset varies with our rounding => ref is
// an fp32 direct-form variant. This round: LLVM DAG-contraction order, what
// clang/nvcc emit for ((dx*dx + dy*dy) + dz*dz) with fp-contract on:
//   inner: fma(dx,dx, round(dy*dy));  outer: fma(dz,dz, inner)
// (differs from R3 in WHICH square is exact vs rounded).

#define FPS_THREADS 1024
#define FPS_PPT 16   // points per thread = N / FPS_THREADS

__global__ __launch_bounds__(FPS_THREADS) void fps_kernel(
    const float* __restrict__ xyz, int* __restrict__ out_idx,
    int N, int S) {
#pragma clang fp contract(off)
  const int b = blockIdx.x;
  const int t = threadIdx.x;
  const float* xb = xyz + (size_t)b * N * 3;

  float px[FPS_PPT], py[FPS_PPT], pz[FPS_PPT], dist[FPS_PPT];
#pragma unroll
  for (int i = 0; i < FPS_PPT; ++i) {
    int p = i * FPS_THREADS + t;
    px[i] = xb[p * 3 + 0];
    py[i] = xb[p * 3 + 1];
    pz[i] = xb[p * 3 + 2];
    dist[i] = FLT_MAX;
  }

  __shared__ float s_v[FPS_THREADS / 64];
  __shared__ int s_p[FPS_THREADS / 64];

  const int wave = t >> 6;
  const int lane = t & 63;
  int farthest = 0;

  for (int s = 0; s < S; ++s) {
    if (t == 0) out_idx[(size_t)b * S + s] = farthest;

    // centroid load: index is block-uniform -> scalarize
    int f = __builtin_amdgcn_readfirstlane(farthest);
    float cx = xb[f * 3 + 0];
    float cy = xb[f * 3 + 1];
    float cz = xb[f * 3 + 2];

    float bestv = -1.0f;
    int bestp = 0x7fffffff;
#pragma unroll
    for (int i = 0; i < FPS_PPT; ++i) {
      float dx = px[i] - cx;
      float dy = py[i] - cy;
      float dz = pz[i] - cz;
      // LLVM DAG contraction of ((dx*dx + dy*dy) + dz*dz):
      float y2 = dy * dy;                          // rounded separately
      float inner = __builtin_fmaf(dx, dx, y2);    // dx^2 exact in fma
      float d = __builtin_fmaf(dz, dz, inner);     // dz^2 exact in fma
      float nd = fminf(dist[i], d);
      dist[i] = nd;
      // strict > : ascending point index within thread => first occurrence
      if (nd > bestv) { bestv = nd; bestp = i * FPS_THREADS + t; }
    }

    // wave-level butterfly argmax reduce; smaller index wins ties
#pragma unroll
    for (int off = 32; off > 0; off >>= 1) {
      float ov = __shfl_xor(bestv, off, 64);
      int op = __shfl_xor(bestp, off, 64);
      if (ov > bestv || (ov == bestv && op < bestp)) { bestv = ov; bestp = op; }
    }

    __syncthreads();  // all reads of s_v/s_p from prev iter done before rewrite
    if (lane == 0) { s_v[wave] = bestv; s_p[wave] = bestp; }
    __syncthreads();

    // every thread redundantly reduces the 16 wave results (broadcast reads)
    float bv = s_v[0];
    int bp = s_p[0];
#pragma unroll
    for (int w = 1; w < FPS_THREADS / 64; ++w) {
      float ov = s_v[w];
      int op = s_p[w];
      if (ov > bv || (ov == bv && op < bp)) { bv = ov; bp = op; }
    }
    farthest = bp;
  }
}

// Gather: out = [ xyz[b][idx[b][s]][c] (B*S*3) , feat[b][idx[b][s]][:] (B*S*C) ]
__global__ void gather_kernel(const float* __restrict__ xyz,
                              const float* __restrict__ feat,
                              const int* __restrict__ idx,
                              float* __restrict__ out,
                              int B, int N, int S, int C) {
  const int c4pr = C >> 2;          // float4s per feat row
  const int nf4 = B * S * c4pr;     // total float4s of feat output
  int tid = blockIdx.x * blockDim.x + threadIdx.x;
  if (tid < nf4) {
    int c4 = tid % c4pr;
    int bs = tid / c4pr;
    int s = bs % S, b = bs / S;
    int p = idx[b * S + s];
    const float4* src = (const float4*)(feat + ((size_t)b * N + p) * C);
    float4* dst = (float4*)(out + (size_t)B * S * 3 + ((size_t)bs) * C);
    dst[c4] = src[c4];
  } else {
    int t2 = tid - nf4;
    int nxyz = B * S * 3;
    if (t2 < nxyz) {
      int c = t2 % 3;
      int bs = t2 / 3;
      int s = bs % S, b = bs / S;
      int p = idx[b * S + s];
      out[t2] = xyz[((size_t)b * N + p) * 3 + c];
    }
  }
}

extern "C" void kernel_launch(void* const* d_in, const int* in_sizes, int n_in,
                              void* d_out, int out_size, void* d_ws, size_t ws_size,
                              hipStream_t stream) {
  const float* xyz = (const float*)d_in[0];
  const float* feat = (const float*)d_in[1];
  float* out = (float*)d_out;

  const int B = 32;
  const int N = in_sizes[0] / (B * 3);        // 16384
  const int C = in_sizes[1] / (B * N);        // 128
  const int S = N / 4;                        // nsample = 0.25 * N = 4096

  int* d_idx = (int*)d_ws;  // B*S int32

  fps_kernel<<<B, FPS_THREADS, 0, stream>>>(xyz, d_idx, N, S);

  int total = B * S * (C >> 2) + B * S * 3;
  int blocks = (total + 255) / 256;
  gather_kernel<<<blocks, 256, 0, stream>>>(xyz, feat, d_idx, out, B, N, S, C);
}

// Round 8
// 11061.130 us; speedup vs baseline: 1.0120x; 1.0120x over previous
//
#include <hip/hip_runtime.h>
#include <hip/hip_bf16.h>
#include <cfloat>

// FPS matching the np reference bit-exactly (R7: PASS, absmax 0).
// FROZEN arithmetic: dx=px-cx; y2=dy*dy; inner=fma(dx,dx,y2); d=fma(dz,dz,inner);
// nd=fminf(dist,d); argmax strict-> first occurrence, ascending index order.
// R8 perf fix: VGPR_Count=40 at R7 proves the 64-float per-thread state was
// demoted to scratch (explains 6560 cy/step vs ~2000 expected, VALUBusy 8%).
// -> macro-generated named scalars (SROA-proof), and 1 barrier/step via
// parity-double-buffered reduction slots.

#define FPS_THREADS 1024

#define REP16(M) M(0) M(1) M(2) M(3) M(4) M(5) M(6) M(7) \
                 M(8) M(9) M(10) M(11) M(12) M(13) M(14) M(15)

__global__ __launch_bounds__(FPS_THREADS) void fps_kernel(
    const float* __restrict__ xyz, int* __restrict__ out_idx,
    int N, int S) {
#pragma clang fp contract(off)
  const int b = blockIdx.x;
  const int t = threadIdx.x;
  const float* xb = xyz + (size_t)b * N * 3;

#define DECLP(k) float px##k, py##k, pz##k, ds##k;
  REP16(DECLP)

#define LOADP(k) { int p = (k) * FPS_THREADS + t;      \
    px##k = xb[p * 3 + 0];                             \
    py##k = xb[p * 3 + 1];                             \
    pz##k = xb[p * 3 + 2];                             \
    ds##k = FLT_MAX; }
  REP16(LOADP)

  __shared__ float s_v[2][FPS_THREADS / 64];
  __shared__ int s_p[2][FPS_THREADS / 64];

  const int wave = t >> 6;
  const int lane = t & 63;
  int farthest = 0;

  for (int s = 0; s < S; ++s) {
    if (t == 0) out_idx[(size_t)b * S + s] = farthest;

    // centroid: block-uniform index -> scalar loads
    int f = __builtin_amdgcn_readfirstlane(farthest);
    float cx = xb[f * 3 + 0];
    float cy = xb[f * 3 + 1];
    float cz = xb[f * 3 + 2];

    float bestv = -1.0f;
    int bestp = 0x7fffffff;

    // FROZEN reference arithmetic (LLVM DAG contraction form):
#define STEPP(k) {                                         \
    float dx = px##k - cx;                                 \
    float dy = py##k - cy;                                 \
    float dz = pz##k - cz;                                 \
    float y2 = dy * dy;                                    \
    float inner = __builtin_fmaf(dx, dx, y2);              \
    float dd = __builtin_fmaf(dz, dz, inner);              \
    float nd = fminf(ds##k, dd);                           \
    ds##k = nd;                                            \
    if (nd > bestv) { bestv = nd; bestp = (k) * FPS_THREADS + t; } }
    REP16(STEPP)

    // wave-level butterfly argmax; smaller index wins ties
#pragma unroll
    for (int off = 32; off > 0; off >>= 1) {
      float ov = __shfl_xor(bestv, off, 64);
      int op = __shfl_xor(bestp, off, 64);
      if (ov > bestv || (ov == bestv && op < bestp)) { bestv = ov; bestp = op; }
    }

    // single barrier per step: parity double-buffer separates prev-step reads
    // (before barrier s) from this-step writes of the other parity.
    const int par = s & 1;
    if (lane == 0) { s_v[par][wave] = bestv; s_p[par][wave] = bestp; }
    __syncthreads();

    float bv = s_v[par][0];
    int bp = s_p[par][0];
#pragma unroll
    for (int w = 1; w < FPS_THREADS / 64; ++w) {
      float ov = s_v[par][w];
      int op = s_p[par][w];
      if (ov > bv || (ov == bv && op < bp)) { bv = ov; bp = op; }
    }
    farthest = bp;
  }
}

// Gather: out = [ xyz[b][idx[b][s]][c] (B*S*3) , feat[b][idx[b][s]][:] (B*S*C) ]
__global__ void gather_kernel(const float* __restrict__ xyz,
                              const float* __restrict__ feat,
                              const int* __restrict__ idx,
                              float* __restrict__ out,
                              int B, int N, int S, int C) {
  const int c4pr = C >> 2;          // float4s per feat row
  const int nf4 = B * S * c4pr;     // total float4s of feat output
  int tid = blockIdx.x * blockDim.x + threadIdx.x;
  if (tid < nf4) {
    int c4 = tid % c4pr;
    int bs = tid / c4pr;
    int s = bs % S, b = bs / S;
    int p = idx[b * S + s];
    const float4* src = (const float4*)(feat + ((size_t)b * N + p) * C);
    float4* dst = (float4*)(out + (size_t)B * S * 3 + ((size_t)bs) * C);
    dst[c4] = src[c4];
  } else {
    int t2 = tid - nf4;
    int nxyz = B * S * 3;
    if (t2 < nxyz) {
      int c = t2 % 3;
      int bs = t2 / 3;
      int s = bs % S, b = bs / S;
      int p = idx[b * S + s];
      out[t2] = xyz[((size_t)b * N + p) * 3 + c];
    }
  }
}

extern "C" void kernel_launch(void* const* d_in, const int* in_sizes, int n_in,
                              void* d_out, int out_size, void* d_ws, size_t ws_size,
                              hipStream_t stream) {
  const float* xyz = (const float*)d_in[0];
  const float* feat = (const float*)d_in[1];
  float* out = (float*)d_out;

  const int B = 32;
  const int N = in_sizes[0] / (B * 3);        // 16384
  const int C = in_sizes[1] / (B * N);        // 128
  const int S = N / 4;                        // nsample = 0.25 * N = 4096

  int* d_idx = (int*)d_ws;  // B*S int32

  fps_kernel<<<B, FPS_THREADS, 0, stream>>>(xyz, d_idx, N, S);

  int total = B * S * (C >> 2) + B * S * 3;
  int blocks = (total + 255) / 256;
  gather_kernel<<<blocks, 256, 0, stream>>>(xyz, feat, d_idx, out, B, N, S, C);
}

// Round 9
// 7195.225 us; speedup vs baseline: 1.5557x; 1.5373x over previous
//
#include <hip/hip_runtime.h>
#include <hip/hip_bf16.h>
#include <cfloat>

// FPS matching the np reference bit-exactly (R7: PASS, absmax 0).
// FROZEN arithmetic: dx=px-cx; y2=dy*dy; inner=fma(dx,dx,y2); d=fma(dz,dz,inner);
// nd=fminf(dist,d); argmax first-occurrence (strict >, ascending index).
// R9: (1) __launch_bounds__(1024,4) -> 128-VGPR budget so the 64-float state
// stays register-resident (R8 proved default budget=40 forces per-step memory
// round-trips ~5k cy/step); (2) packed u64 (value,~idx) argmax keys -- same
// winner provably (dist >= 0 -> float bit order == value order), shorter chain.

#define FPS_THREADS 1024

#define REP16(M) M(0) M(1) M(2) M(3) M(4) M(5) M(6) M(7) \
                 M(8) M(9) M(10) M(11) M(12) M(13) M(14) M(15)

__global__ __launch_bounds__(FPS_THREADS, 4) void fps_kernel(
    const float* __restrict__ xyz, int* __restrict__ out_idx,
    int N, int S) {
#pragma clang fp contract(off)
  const int b = blockIdx.x;
  const int t = threadIdx.x;
  const float* xb = xyz + (size_t)b * N * 3;

#define DECLP(k) float px##k, py##k, pz##k, ds##k;
  REP16(DECLP)

#define LOADP(k) { int p = (k) * FPS_THREADS + t;      \
    px##k = xb[p * 3 + 0];                             \
    py##k = xb[p * 3 + 1];                             \
    pz##k = xb[p * 3 + 2];                             \
    ds##k = FLT_MAX; }
  REP16(LOADP)

  __shared__ unsigned long long s_k[2][FPS_THREADS / 64];

  const int wave = t >> 6;
  const int lane = t & 63;
  int farthest = 0;

  for (int s = 0; s < S; ++s) {
    if (t == 0) out_idx[(size_t)b * S + s] = farthest;

    // centroid: block-uniform index -> scalar loads
    int f = __builtin_amdgcn_readfirstlane(farthest);
    float cx = xb[f * 3 + 0];
    float cy = xb[f * 3 + 1];
    float cz = xb[f * 3 + 2];

    // packed key: (float bits << 32) | (0xFFFFFFFF - idx)
    // max over keys == (max value, then smallest index) -- dist >= 0 always.
    unsigned long long bestk = 0;

    // FROZEN reference arithmetic (LLVM DAG contraction form):
#define STEPP(k) {                                               \
    float dx = px##k - cx;                                       \
    float dy = py##k - cy;                                       \
    float dz = pz##k - cz;                                       \
    float y2 = dy * dy;                                          \
    float inner = __builtin_fmaf(dx, dx, y2);                    \
    float dd = __builtin_fmaf(dz, dz, inner);                    \
    float nd = fminf(ds##k, dd);                                 \
    ds##k = nd;                                                  \
    unsigned long long key =                                     \
        ((unsigned long long)__float_as_uint(nd) << 32) |        \
        (unsigned long long)(0xFFFFFFFFu - (unsigned)((k) * FPS_THREADS + t)); \
    if (key > bestk) bestk = key; }
    REP16(STEPP)

    // wave-level butterfly max over packed keys
#pragma unroll
    for (int off = 32; off > 0; off >>= 1) {
      unsigned long long ok = __shfl_xor(bestk, off, 64);
      if (ok > bestk) bestk = ok;
    }

    // single barrier per step: parity double-buffer
    const int par = s & 1;
    if (lane == 0) s_k[par][wave] = bestk;
    __syncthreads();

    unsigned long long bk = s_k[par][0];
#pragma unroll
    for (int w = 1; w < FPS_THREADS / 64; ++w) {
      unsigned long long ok = s_k[par][w];
      if (ok > bk) bk = ok;
    }
    farthest = (int)(0xFFFFFFFFu - (unsigned)(bk & 0xFFFFFFFFu));
  }
}

// Gather: out = [ xyz[b][idx[b][s]][c] (B*S*3) , feat[b][idx[b][s]][:] (B*S*C) ]
__global__ void gather_kernel(const float* __restrict__ xyz,
                              const float* __restrict__ feat,
                              const int* __restrict__ idx,
                              float* __restrict__ out,
                              int B, int N, int S, int C) {
  const int c4pr = C >> 2;          // float4s per feat row
  const int nf4 = B * S * c4pr;     // total float4s of feat output
  int tid = blockIdx.x * blockDim.x + threadIdx.x;
  if (tid < nf4) {
    int c4 = tid % c4pr;
    int bs = tid / c4pr;
    int s = bs % S, b = bs / S;
    int p = idx[b * S + s];
    const float4* src = (const float4*)(feat + ((size_t)b * N + p) * C);
    float4* dst = (float4*)(out + (size_t)B * S * 3 + ((size_t)bs) * C);
    dst[c4] = src[c4];
  } else {
    int t2 = tid - nf4;
    int nxyz = B * S * 3;
    if (t2 < nxyz) {
      int c = t2 % 3;
      int bs = t2 / 3;
      int s = bs % S, b = bs / S;
      int p = idx[b * S + s];
      out[t2] = xyz[((size_t)b * N + p) * 3 + c];
    }
  }
}

extern "C" void kernel_launch(void* const* d_in, const int* in_sizes, int n_in,
                              void* d_out, int out_size, void* d_ws, size_t ws_size,
                              hipStream_t stream) {
  const float* xyz = (const float*)d_in[0];
  const float* feat = (const float*)d_in[1];
  float* out = (float*)d_out;

  const int B = 32;
  const int N = in_sizes[0] / (B * 3);        // 16384
  const int C = in_sizes[1] / (B * N);        // 128
  const int S = N / 4;                        // nsample = 0.25 * N = 4096

  int* d_idx = (int*)d_ws;  // B*S int32

  fps_kernel<<<B, FPS_THREADS, 0, stream>>>(xyz, d_idx, N, S);

  int total = B * S * (C >> 2) + B * S * 3;
  int blocks = (total + 255) / 256;
  gather_kernel<<<blocks, 256, 0, stream>>>(xyz, feat, d_idx, out, B, N, S, C);
}

// Round 10
// 7134.289 us; speedup vs baseline: 1.5690x; 1.0085x over previous
//
#include <hip/hip_runtime.h>
#include <hip/hip_bf16.h>
#include <cfloat>

// FPS matching the np reference bit-exactly (R7: PASS, absmax 0).
// FROZEN arithmetic: dx=px-cx; y2=dy*dy; inner=fma(dx,dx,y2); d=fma(dz,dz,inner);
// nd=fminf(dist,d); winner = max (value, smallest index) via packed u64 keys.
// R10: R9 showed VGPR=60 -> compiler REMATERIALIZES the 48 coord loads inside
// the step loop (~3000 cy/step of L1 traffic). Pin coords with empty asm so
// they must stay register-resident; hoist inverted-index constants.

#define FPS_THREADS 1024

#define REP16(M) M(0) M(1) M(2) M(3) M(4) M(5) M(6) M(7) \
                 M(8) M(9) M(10) M(11) M(12) M(13) M(14) M(15)

__global__ __launch_bounds__(FPS_THREADS, 4) void fps_kernel(
    const float* __restrict__ xyz, int* __restrict__ out_idx,
    int N, int S) {
#pragma clang fp contract(off)
  const int b = blockIdx.x;
  const int t = threadIdx.x;
  const float* xb = xyz + (size_t)b * N * 3;

#define DECLP(k) float px##k, py##k, pz##k, ds##k; unsigned inv##k;
  REP16(DECLP)

#define LOADP(k) { int p = (k) * FPS_THREADS + t;      \
    px##k = xb[p * 3 + 0];                             \
    py##k = xb[p * 3 + 1];                             \
    pz##k = xb[p * 3 + 2];                             \
    ds##k = FLT_MAX;                                   \
    inv##k = 0xFFFFFFFFu - (unsigned)p;                \
    asm("" : "+v"(px##k), "+v"(py##k), "+v"(pz##k)); }
  REP16(LOADP)

  __shared__ unsigned long long s_k[2][FPS_THREADS / 64];

  const int wave = t >> 6;
  const int lane = t & 63;
  int farthest = 0;

  for (int s = 0; s < S; ++s) {
    if (t == 0) out_idx[(size_t)b * S + s] = farthest;

    // centroid: block-uniform index -> scalar loads
    int f = __builtin_amdgcn_readfirstlane(farthest);
    float cx = xb[f * 3 + 0];
    float cy = xb[f * 3 + 1];
    float cz = xb[f * 3 + 2];

    // packed key: (float bits << 32) | (0xFFFFFFFF - idx)
    // max over keys == (max value, then smallest index); dist >= 0 always.
    unsigned long long bestk = 0;

    // FROZEN reference arithmetic (LLVM DAG contraction form):
#define STEPP(k) {                                               \
    float dx = px##k - cx;                                       \
    float dy = py##k - cy;                                       \
    float dz = pz##k - cz;                                       \
    float y2 = dy * dy;                                          \
    float inner = __builtin_fmaf(dx, dx, y2);                    \
    float dd = __builtin_fmaf(dz, dz, inner);                    \
    float nd = fminf(ds##k, dd);                                 \
    ds##k = nd;                                                  \
    unsigned long long key =                                     \
        ((unsigned long long)__float_as_uint(nd) << 32) |        \
        (unsigned long long)inv##k;                              \
    if (key > bestk) bestk = key; }
    REP16(STEPP)

    // wave-level butterfly max over packed keys
#pragma unroll
    for (int off = 32; off > 0; off >>= 1) {
      unsigned long long ok = __shfl_xor(bestk, off, 64);
      if (ok > bestk) bestk = ok;
    }

    // single barrier per step: parity double-buffer
    const int par = s & 1;
    if (lane == 0) s_k[par][wave] = bestk;
    __syncthreads();

    unsigned long long bk = s_k[par][0];
#pragma unroll
    for (int w = 1; w < FPS_THREADS / 64; ++w) {
      unsigned long long ok = s_k[par][w];
      if (ok > bk) bk = ok;
    }
    farthest = (int)(0xFFFFFFFFu - (unsigned)(bk & 0xFFFFFFFFu));
  }
}

// Gather: out = [ xyz[b][idx[b][s]][c] (B*S*3) , feat[b][idx[b][s]][:] (B*S*C) ]
__global__ void gather_kernel(const float* __restrict__ xyz,
                              const float* __restrict__ feat,
                              const int* __restrict__ idx,
                              float* __restrict__ out,
                              int B, int N, int S, int C) {
  const int c4pr = C >> 2;          // float4s per feat row
  const int nf4 = B * S * c4pr;     // total float4s of feat output
  int tid = blockIdx.x * blockDim.x + threadIdx.x;
  if (tid < nf4) {
    int c4 = tid % c4pr;
    int bs = tid / c4pr;
    int s = bs % S, b = bs / S;
    int p = idx[b * S + s];
    const float4* src = (const float4*)(feat + ((size_t)b * N + p) * C);
    float4* dst = (float4*)(out + (size_t)B * S * 3 + ((size_t)bs) * C);
    dst[c4] = src[c4];
  } else {
    int t2 = tid - nf4;
    int nxyz = B * S * 3;
    if (t2 < nxyz) {
      int c = t2 % 3;
      int bs = t2 / 3;
      int s = bs % S, b = bs / S;
      int p = idx[b * S + s];
      out[t2] = xyz[((size_t)b * N + p) * 3 + c];
    }
  }
}

extern "C" void kernel_launch(void* const* d_in, const int* in_sizes, int n_in,
                              void* d_out, int out_size, void* d_ws, size_t ws_size,
                              hipStream_t stream) {
  const float* xyz = (const float*)d_in[0];
  const float* feat = (const float*)d_in[1];
  float* out = (float*)d_out;

  const int B = 32;
  const int N = in_sizes[0] / (B * 3);        // 16384
  const int C = in_sizes[1] / (B * N);        // 128
  const int S = N / 4;                        // nsample = 0.25 * N = 4096

  int* d_idx = (int*)d_ws;  // B*S int32

  fps_kernel<<<B, FPS_THREADS, 0, stream>>>(xyz, d_idx, N, S);

  int total = B * S * (C >> 2) + B * S * 3;
  int blocks = (total + 255) / 256;
  gather_kernel<<<blocks, 256, 0, stream>>>(xyz, feat, d_idx, out, B, N, S, C);
}